// Round 10
// baseline (572.008 us; speedup 1.0000x reference)
//
#include <hip/hip_runtime.h>
#include <hip/hip_bf16.h>

typedef __bf16 bf16;
typedef __bf16 bf16x2 __attribute__((ext_vector_type(2)));
typedef __bf16 bf16x8 __attribute__((ext_vector_type(8)));
typedef float floatx4 __attribute__((ext_vector_type(4)));
typedef float floatx2 __attribute__((ext_vector_type(2)));

__device__ __forceinline__ float silu_f(float x) {
    float e = __expf(-x);
    return x * __builtin_amdgcn_rcpf(1.0f + e);
}

__device__ __forceinline__ float2 unpack_bf2(unsigned v) {
    float2 r;
    r.x = __uint_as_float(v << 16);
    r.y = __uint_as_float(v & 0xFFFF0000u);
    return r;
}

// 8 bf16 -> 8 f32 via bit ops (2 VALU per pair)
__device__ __forceinline__ void unpack8(const bf16* p, float* o) {
    uint4 u = *(const uint4*)p;
    float2 a = unpack_bf2(u.x); o[0]=a.x; o[1]=a.y;
    float2 b = unpack_bf2(u.y); o[2]=b.x; o[3]=b.y;
    float2 c = unpack_bf2(u.z); o[4]=c.x; o[5]=c.y;
    float2 d = unpack_bf2(u.w); o[6]=d.x; o[7]=d.y;
}

// async global -> LDS, 16B per lane; lds dest = base + lane*16 (HW rule)
__device__ __forceinline__ void gll16(const bf16* g, bf16* l) {
    __builtin_amdgcn_global_load_lds((const __attribute__((address_space(1))) void*)g,
                                     (__attribute__((address_space(3))) void*)l, 16, 0, 0);
}

// =================== init: setup (Zp/Zb/h) + WmT(l=0) transpose only ===================
__global__ __launch_bounds__(256) void init_kernel(
    const float* __restrict__ Z, const float* __restrict__ noise,
    const int* __restrict__ nl, const float* __restrict__ sig,
    const int* __restrict__ Aarr, const int* __restrict__ posa, const int* __restrict__ Barr,
    const float* __restrict__ atom_emb, const float* __restrict__ pos_emb,
    const float* __restrict__ block_emb,
    const float* __restrict__ Wm,
    float* __restrict__ Zp, float* __restrict__ Zb0, float* __restrict__ Zb,
    float* __restrict__ hf, bf16* __restrict__ hb,
    bf16* __restrict__ WmT)
{
    __shared__ float zsh[12];
    __shared__ float tile[32][33];
    int bid = blockIdx.x, tid = threadIdx.x;
    if (bid < 8192) {
        int b = bid, g = b >> 10;
        if (tid < 12) {
            float sg = sig[nl[g]];
            int idx = b*12 + tid;
            float zp = Z[idx] + noise[idx]*sg;
            Zp[idx] = zp;
            zsh[tid] = zp;
        }
        __syncthreads();
        if (tid < 3) {
            float v = 0.25f*(zsh[tid] + zsh[3+tid] + zsh[6+tid] + zsh[9+tid]);
            Zb0[b*3+tid] = v; Zb[b*3+tid] = v;
        }
        int ai[4], pi[4];
        #pragma unroll
        for (int a = 0; a < 4; a++) { ai[a] = Aarr[b*4+a]*512; pi[a] = posa[b*4+a]*512; }
        int bb = Barr[b]*512;
        #pragma unroll
        for (int cc = 0; cc < 2; cc++) {
            int c = tid + cc*256;
            float s = 0.0f;
            #pragma unroll
            for (int a = 0; a < 4; a++) s += atom_emb[ai[a]+c] + pos_emb[pi[a]+c];
            s = 0.25f*s + block_emb[bb+c];
            hf[(size_t)b*512+c] = s;
            hb[(size_t)b*512+c] = (bf16)s;
        }
        return;
    }
    // WmT layer-0 transpose (needed by knn_pgemm0 itself): 256 tiles of 32x32
    int rem = bid - 8192;
    int bx = rem & 15, by = rem >> 4;
    int tx = tid & 31, ty = tid >> 5;     // 32 x 8
    #pragma unroll
    for (int i = 0; i < 32; i += 8)
        tile[ty+i][tx] = Wm[(size_t)(by*32+ty+i)*512 + bx*32+tx];
    __syncthreads();
    #pragma unroll
    for (int i = 0; i < 32; i += 8)
        WmT[(size_t)(bx*32+ty+i)*512 + by*32+tx] = (bf16)tile[tx][ty+i];
}

// =================== KNN body: one wave per dst block; packed-fp32 distances ===================
__device__ void knn_body(int kb, const float* __restrict__ Zp, const int* __restrict__ seg,
                         int* __restrict__ nbr) {
    int wid = threadIdx.x >> 6;
    int lane = threadIdx.x & 63;
    int r = ((kb & 7) << 10) + ((kb >> 3) << 2) + wid;   // XCD-local graph
    int g = r >> 10;
    int il = r & 1023;
    int base = g << 10;
    int segr = seg[r];
    float za[4][3];
    #pragma unroll
    for (int a = 0; a < 4; a++)
        #pragma unroll
        for (int d = 0; d < 3; d++)
            za[a][d] = Zp[r*12 + a*3 + d];
    floatx2 ax[4], ay[4], az[4];
    #pragma unroll
    for (int a = 0; a < 4; a++) {
        ax[a] = (floatx2){za[a][0], za[a][0]};
        ay[a] = (floatx2){za[a][1], za[a][1]};
        az[a] = (floatx2){za[a][2], za[a][2]};
    }
    float dist[16];
    unsigned smask = 0;
    #pragma unroll
    for (int t = 0; t < 16; t++) {
        int jb = base + t*64 + lane;
        const float4* p = (const float4*)(Zp + (size_t)jb*12);
        float4 v0 = p[0], v1 = p[1], v2 = p[2];
        floatx2 bx0 = {v0.x, v0.w}, by0 = {v0.y, v1.x}, bz0 = {v0.z, v1.y};
        floatx2 bx1 = {v1.z, v2.y}, by1 = {v1.w, v2.z}, bz1 = {v2.x, v2.w};
        floatx2 mn = {3.0e38f, 3.0e38f};
        #pragma unroll
        for (int a = 0; a < 4; a++) {
            floatx2 dx = ax[a] - bx0, dy = ay[a] - by0, dz = az[a] - bz0;
            floatx2 dd = dx*dx + dy*dy + dz*dz;      // v_pk_mul/fma_f32
            mn.x = fminf(mn.x, dd.x); mn.y = fminf(mn.y, dd.y);
            dx = ax[a] - bx1; dy = ay[a] - by1; dz = az[a] - bz1;
            dd = dx*dx + dy*dy + dz*dz;
            mn.x = fminf(mn.x, dd.x); mn.y = fminf(mn.y, dd.y);
        }
        dist[t] = fminf(mn.x, mn.y);
        if (seg[jb] == segr) smask |= (1u << t);
    }
    const float INF = 3.0e38f;
    for (int phase = 0; phase < 2; phase++) {
        float wd[16];
        #pragma unroll
        for (int t = 0; t < 16; t++) {
            bool ok = (phase == 0) ? (((smask >> t) & 1u) && (t*64 + lane != il))
                                   : (!((smask >> t) & 1u));
            wd[t] = ok ? dist[t] : INF;
        }
        for (int it = 0; it < 9; it++) {
            float bd = wd[0]; int bt = 0;
            #pragma unroll
            for (int t = 1; t < 16; t++) { if (wd[t] < bd) { bd = wd[t]; bt = t; } }
            float mv = bd;
            #pragma unroll
            for (int off = 32; off >= 1; off >>= 1) mv = fminf(mv, __shfl_xor(mv, off, 64));
            unsigned long long msk = __ballot(bd == mv);
            int wl = __ffsll(msk) - 1;
            int wt = __shfl(bt, wl, 64);
            if (lane == 0) nbr[r*18 + phase*9 + it] = base + wt*64 + wl;
            bool amwin = (lane == wl);
            #pragma unroll
            for (int t = 0; t < 16; t++) if (amwin && t == wt) wd[t] = INF;
        }
    }
}

// =================== block GEMM (mode-0 only): 128x64 tile, LDS staging (fused kernel) ===================
__device__ void gemm0_body(const bf16* __restrict__ A, const bf16* __restrict__ BT,
                           bf16* __restrict__ Pb, int bid)
{
    __shared__ alignas(16) bf16 sA[128*32];
    __shared__ alignas(16) bf16 sB[64*32];
    int mt = bid & 63, nt = bid >> 6;
    int m0 = mt*128, n0 = nt*64;
    int tid = threadIdx.x, lane = tid & 63, w = tid >> 6;
    int wm = w & 1, wn = w >> 1;
    int lm = lane & 15, q = lane >> 4;

    // staging: physical chunk p holds logical chunk (row=p>>2, qt=(p&3)^((row>>1)&3))
    int pA0 = w*128 + lane, pA1 = pA0 + 64, pB = w*64 + lane;
    int rA0 = pA0 >> 2, qA0 = (pA0 & 3) ^ ((rA0 >> 1) & 3);
    int rA1 = pA1 >> 2, qA1 = (pA1 & 3) ^ ((rA1 >> 1) & 3);
    int rB  = pB  >> 2, qB  = (pB  & 3) ^ ((rB  >> 1) & 3);
    const bf16* gA0 = A  + (size_t)(m0 + rA0)*512 + qA0*8;
    const bf16* gA1 = A  + (size_t)(m0 + rA1)*512 + qA1*8;
    const bf16* gB  = BT + (size_t)(n0 + rB )*512 + qB*8;
    int dA0 = (w*128)*8, dA1 = (w*128 + 64)*8, dB = (w*64)*8;

    // fragment read offsets (swizzle depends only on lm)
    int swq = (q ^ ((lm >> 1) & 3)) * 8;
    int offA[4], offB[2];
    #pragma unroll
    for (int tm = 0; tm < 4; tm++) offA[tm] = (wm*64 + tm*16 + lm)*32 + swq;
    #pragma unroll
    for (int tn = 0; tn < 2; tn++) offB[tn] = (wn*32 + tn*16 + lm)*32 + swq;

    floatx4 zv = {0.0f, 0.0f, 0.0f, 0.0f};
    floatx4 acc[4][2];
    #pragma unroll
    for (int i = 0; i < 4; i++)
        #pragma unroll
        for (int j = 0; j < 2; j++) acc[i][j] = zv;

    for (int k0 = 0; k0 < 512; k0 += 32) {
        gll16(gA0 + k0, sA + dA0);
        gll16(gA1 + k0, sA + dA1);
        gll16(gB  + k0, sB + dB);
        __syncthreads();
        bf16x8 af[4], bfr[2];
        #pragma unroll
        for (int tm = 0; tm < 4; tm++) af[tm] = *(const bf16x8*)(sA + offA[tm]);
        #pragma unroll
        for (int tn = 0; tn < 2; tn++) bfr[tn] = *(const bf16x8*)(sB + offB[tn]);
        #pragma unroll
        for (int tm = 0; tm < 4; tm++)
            #pragma unroll
            for (int tn = 0; tn < 2; tn++)
                acc[tm][tn] = __builtin_amdgcn_mfma_f32_16x16x32_bf16(af[tm], bfr[tn], acc[tm][tn], 0, 0, 0);
        __syncthreads();
    }

    #pragma unroll
    for (int tm = 0; tm < 4; tm++)
        #pragma unroll
        for (int tn = 0; tn < 2; tn++)
            #pragma unroll
            for (int rr = 0; rr < 4; rr++) {
                int row = m0 + wm*64 + tm*16 + q*4 + rr;
                int col = n0 + wn*32 + tn*16 + lm;
                Pb[(size_t)row*512 + col] = (bf16)acc[tm][tn][rr];
            }
}

// =================== wave-GEMM: barrier-free, LDS-free; one wave = 32x32 output tile ===================
// 4096 waves (1024 blocks x 4). Fragments loaded DIRECTLY global->reg (bf16x8, 16B aligned),
// register double-buffered; waves fully decoupled (no __syncthreads, no LDS, no inline asm).
// mode 0: Pb = bf16(acc)
// mode 1: hf += silu(acc); hb (l<2) or shp (l==2); wn==0 waves fold Zb += zacc/18;
//         l==2 additionally folds graph_repr (atomics) and (wn==0) pred_noise + loss
// mode 2: t = silu(acc + b1[col]); out_e[g] += sum(t . W2) (one atomic per wave)
template<int MODE>
__global__ __launch_bounds__(256) void wgemm_kernel(
    const bf16* __restrict__ A, const bf16* __restrict__ BT,
    bf16* __restrict__ Pb, float* __restrict__ hf,
    bf16* __restrict__ hb, bf16* __restrict__ shp,
    const float* __restrict__ b1, const float* __restrict__ W2,
    float* __restrict__ out_e,
    float* __restrict__ Zb, const float* __restrict__ zacc,
    const float* __restrict__ Zb0, const float* __restrict__ noise,
    float* __restrict__ out_pn, float* __restrict__ out_loss,
    float* __restrict__ out_gr)
{
    int tid = threadIdx.x, lane = tid & 63, w = tid >> 6;
    int wid = blockIdx.x*4 + w;          // 0..4095
    int wm = wid >> 4, wn = wid & 15;    // 256 m-tiles x 16 n-tiles
    int r0 = wm*32, c0 = wn*32;
    int lm = lane & 15, q = lane >> 4;

    const bf16* pa0 = A  + (size_t)(r0 + lm)*512      + q*8;
    const bf16* pa1 = A  + (size_t)(r0 + 16 + lm)*512 + q*8;
    const bf16* pb0 = BT + (size_t)(c0 + lm)*512      + q*8;
    const bf16* pb1 = BT + (size_t)(c0 + 16 + lm)*512 + q*8;

    floatx4 zv = {0.0f, 0.0f, 0.0f, 0.0f};
    floatx4 acc[2][2] = {{zv, zv}, {zv, zv}};

    // register double-buffer: E = even k-steps, O = odd k-steps
    bf16x8 aE0 = *(const bf16x8*)(pa0);
    bf16x8 aE1 = *(const bf16x8*)(pa1);
    bf16x8 bE0 = *(const bf16x8*)(pb0);
    bf16x8 bE1 = *(const bf16x8*)(pb1);
    #pragma unroll
    for (int t = 0; t < 8; t++) {
        const int kO = t*64 + 32;
        bf16x8 aO0 = *(const bf16x8*)(pa0 + kO);
        bf16x8 aO1 = *(const bf16x8*)(pa1 + kO);
        bf16x8 bO0 = *(const bf16x8*)(pb0 + kO);
        bf16x8 bO1 = *(const bf16x8*)(pb1 + kO);
        acc[0][0] = __builtin_amdgcn_mfma_f32_16x16x32_bf16(aE0, bE0, acc[0][0], 0, 0, 0);
        acc[0][1] = __builtin_amdgcn_mfma_f32_16x16x32_bf16(aE0, bE1, acc[0][1], 0, 0, 0);
        acc[1][0] = __builtin_amdgcn_mfma_f32_16x16x32_bf16(aE1, bE0, acc[1][0], 0, 0, 0);
        acc[1][1] = __builtin_amdgcn_mfma_f32_16x16x32_bf16(aE1, bE1, acc[1][1], 0, 0, 0);
        if (t < 7) {
            const int kE = t*64 + 64;
            aE0 = *(const bf16x8*)(pa0 + kE);
            aE1 = *(const bf16x8*)(pa1 + kE);
            bE0 = *(const bf16x8*)(pb0 + kE);
            bE1 = *(const bf16x8*)(pb1 + kE);
        }
        acc[0][0] = __builtin_amdgcn_mfma_f32_16x16x32_bf16(aO0, bO0, acc[0][0], 0, 0, 0);
        acc[0][1] = __builtin_amdgcn_mfma_f32_16x16x32_bf16(aO0, bO1, acc[0][1], 0, 0, 0);
        acc[1][0] = __builtin_amdgcn_mfma_f32_16x16x32_bf16(aO1, bO0, acc[1][0], 0, 0, 0);
        acc[1][1] = __builtin_amdgcn_mfma_f32_16x16x32_bf16(aO1, bO1, acc[1][1], 0, 0, 0);
    }

    if (MODE == 2) {
        float esum = 0.0f;
        #pragma unroll
        for (int tn = 0; tn < 2; tn++) {
            int col = c0 + tn*16 + lm;
            float bb = b1[col];
            float w2 = W2[col];
            #pragma unroll
            for (int tm = 0; tm < 2; tm++)
                #pragma unroll
                for (int rr = 0; rr < 4; rr++)
                    esum += silu_f(acc[tm][tn][rr] + bb) * w2;
        }
        #pragma unroll
        for (int off = 32; off >= 1; off >>= 1) esum += __shfl_xor(esum, off, 64);
        if (lane == 0) atomicAdd(&out_e[wm >> 5], esum);
        return;
    }

    if (MODE == 1 && wn == 0) {          // fold zb_apply: rows r0..r0+31 (wave-exclusive)
        #pragma unroll
        for (int o = 0; o < 2; o++) {
            int i = o*64 + lane;
            if (i < 96) Zb[r0*3 + i] += zacc[r0*3 + i] * (1.0f/18.0f);
        }
    }

    float colsum[2] = {0.0f, 0.0f};
    #pragma unroll
    for (int tm = 0; tm < 2; tm++) {
        #pragma unroll
        for (int tn = 0; tn < 2; tn++) {
            #pragma unroll
            for (int rr = 0; rr < 4; rr++) {
                int row = r0 + tm*16 + q*4 + rr;
                int col = c0 + tn*16 + lm;
                size_t o = (size_t)row*512 + col;
                float v = acc[tm][tn][rr];
                if (MODE == 0) {
                    Pb[o] = (bf16)v;
                } else {
                    float nh = hf[o] + silu_f(v);
                    hf[o] = nh;
                    colsum[tn] += nh;
                    if (shp) shp[o] = (bf16)silu_f(nh);   // l==2: hb dead, sh needed
                    else     hb[o] = (bf16)nh;            // l<2: hb feeds next pgemm
                }
            }
        }
    }

    if (MODE == 1 && shp) {              // l==2 fold: graph_repr + pred_noise + loss
        int g = wm >> 5;
        #pragma unroll
        for (int tn = 0; tn < 2; tn++) {
            float v = colsum[tn];
            v += __shfl_xor(v, 16, 64);
            v += __shfl_xor(v, 32, 64);
            if (q == 0) atomicAdd(&out_gr[g*512 + c0 + tn*16 + lm], v);
        }
        if (wn == 0) {
            // pred_noise + loss for units of rows r0..r0+31 (Zb updated above by this wave)
            float per2 = 0.0f;
            #pragma unroll
            for (int j = 0; j < 2; j++) {
                int u = r0*4 + lane*2 + j;
                int b = u >> 2;
                #pragma unroll
                for (int d = 0; d < 3; d++) {
                    float dv = Zb[b*3 + d] - Zb0[b*3 + d];
                    out_pn[(size_t)u*3 + d] = dv;
                    float e = dv - noise[(size_t)u*3 + d];
                    per2 += e*e;
                }
            }
            #pragma unroll
            for (int off = 32; off >= 1; off >>= 1) per2 += __shfl_xor(per2, off, 64);
            if (lane == 0) atomicAdd(out_loss, per2 * (1.0f/16.0f));
        }
    }
}

// fused: [0,512) P-GEMM layer 0; [512,2560) KNN; [2560,4096) transposes l>0;
//        [4096,4108) ebias; [4108,4125) output zeroing
__global__ __launch_bounds__(256) void knn_pgemm0_kernel(const bf16* __restrict__ hb,
                                                         const bf16* __restrict__ WmT,
                                                         bf16* __restrict__ Pb,
                                                         const float* __restrict__ Zp,
                                                         const int* __restrict__ seg,
                                                         int* __restrict__ nbr,
                                                         const float* __restrict__ Wm,
                                                         const float* __restrict__ Wu,
                                                         const float* __restrict__ W1,
                                                         bf16* __restrict__ WmTw,
                                                         bf16* __restrict__ WuT,
                                                         bf16* __restrict__ W1T,
                                                         const float* __restrict__ edge_emb,
                                                         const float* __restrict__ We,
                                                         float* __restrict__ ebias,
                                                         float* __restrict__ out_gr,
                                                         float* __restrict__ out_e,
                                                         float* __restrict__ out_loss) {
    __shared__ float ttile[32][33];
    int bid = blockIdx.x, tid = threadIdx.x;
    if (bid < 512) {
        gemm0_body(hb, WmT, Pb, bid);
        return;
    }
    if (bid < 2560) {
        knn_body(bid - 512, Zp, seg, nbr);
        return;
    }
    int tb = bid - 2560;
    if (tb < 1536) {   // 6 matrices (Wm l=1,2; Wu l=0..2; W1) x 256 tiles
        int z = 1 + (tb >> 8), rem = tb & 255;
        int bx = rem & 15, by = rem >> 4;
        int tx = tid & 31, ty = tid >> 5;     // 32 x 8
        const float* src; bf16* dst;
        if (z < 3)      { src = Wm + (size_t)z*262144;     dst = WmTw + (size_t)z*262144; }
        else if (z < 6) { src = Wu + (size_t)(z-3)*262144; dst = WuT + (size_t)(z-3)*262144; }
        else            { src = W1;                        dst = W1T; }
        #pragma unroll
        for (int i = 0; i < 32; i += 8)
            ttile[ty+i][tx] = src[(size_t)(by*32+ty+i)*512 + bx*32+tx];
        __syncthreads();
        #pragma unroll
        for (int i = 0; i < 32; i += 8)
            dst[(size_t)(bx*32+ty+i)*512 + by*32+tx] = (bf16)ttile[tx][ty+i];
        return;
    }
    tb -= 1536;
    if (tb < 12) {
        int gid = tb*256 + tid;
        int l = gid >> 10, t = (gid >> 9) & 1, c = gid & 511;
        float s = 0.0f;
        #pragma unroll 8
        for (int e = 0; e < 64; e++)
            s += edge_emb[t*64 + e] * We[(size_t)(l*64 + e)*512 + c];
        ebias[gid] = s;
        return;
    }
    tb -= 12;
    int k = tb*256 + tid;
    if (k < 4096) out_gr[k] = 0.0f;
    else if (k < 4104) out_e[k-4096] = 0.0f;
    else if (k == 4104) out_loss[0] = 0.0f;
}

// =================== edge aggregation: one WAVE per dst block, 8 ch/lane ===================
__global__ __launch_bounds__(256) void edge_kernel(const bf16* __restrict__ Pb, const float* __restrict__ ebias,
                                                   const float* __restrict__ wz, const float* __restrict__ Zb,
                                                   const int* __restrict__ nbr, bf16* __restrict__ msum,
                                                   float* __restrict__ zacc) {
    int bid = blockIdx.x, tid = threadIdx.x;
    int lane = tid & 63, wid = tid >> 6;
    int b = ((bid & 7) << 10) | ((bid >> 3) << 2) | wid;   // XCD-local graph, 4 dst blocks/block
    __shared__ int srcs[4][18];
    if (tid < 72) {
        int w2 = tid / 18, e2 = tid - w2*18;
        int bb = ((bid & 7) << 10) | ((bid >> 3) << 2) | w2;
        srcs[w2][e2] = nbr[bb*18 + e2];
    }
    __syncthreads();
    int c0 = lane << 3;     // 8 channels per lane
    float pd[8], eb0[8], eb1[8], wv[8];
    unpack8(Pb + (size_t)b*512 + c0, pd);
    *(float4*)(eb0)   = *(const float4*)(ebias + c0);
    *(float4*)(eb0+4) = *(const float4*)(ebias + c0 + 4);
    *(float4*)(eb1)   = *(const float4*)(ebias + 512 + c0);
    *(float4*)(eb1+4) = *(const float4*)(ebias + 512 + c0 + 4);
    *(float4*)(wv)    = *(const float4*)(wz + c0);
    *(float4*)(wv+4)  = *(const float4*)(wz + c0 + 4);
    float ms[8];
    #pragma unroll
    for (int j = 0; j < 8; j++) ms[j] = 0.0f;
    float pdot[18];
    #pragma unroll
    for (int e = 0; e < 18; e++) {
        int s = srcs[wid][e];
        float pv[8];
        unpack8(Pb + (size_t)s*512 + c0, pv);
        float dot = 0.0f;
        #pragma unroll
        for (int j = 0; j < 8; j++) {
            float base = (e < 9) ? eb0[j] : eb1[j];     // e compile-time after unroll
            float m = silu_f(pv[j] + pd[j] + base);
            ms[j] += m;
            dot += m * wv[j];
        }
        pdot[e] = dot;
    }
    bf16x8 mp;
    #pragma unroll
    for (int j = 0; j < 8; j++) mp[j] = (bf16)ms[j];
    *(bf16x8*)(msum + (size_t)b*512 + c0) = mp;
    // wave-reduce each pdot[e] (butterfly -> every lane has full sum)
    #pragma unroll
    for (int e = 0; e < 18; e++) {
        float v = pdot[e];
        #pragma unroll
        for (int off = 32; off >= 1; off >>= 1) v += __shfl_xor(v, off, 64);
        pdot[e] = v;
    }
    // lane e takes edge e: select own dot, tanh, z-term; reduce 3 comps over lanes
    float dotv = 0.0f;
    #pragma unroll
    for (int e = 0; e < 18; e++) dotv = (lane == e) ? pdot[e] : dotv;
    float coef = tanhf(dotv);
    float t3[3] = {0.0f, 0.0f, 0.0f};
    if (lane < 18) {
        int se = srcs[wid][lane];
        #pragma unroll
        for (int d = 0; d < 3; d++)
            t3[d] = (Zb[se*3 + d] - Zb[b*3 + d]) * coef;
    }
    #pragma unroll
    for (int off = 16; off >= 1; off >>= 1) {
        t3[0] += __shfl_xor(t3[0], off, 64);
        t3[1] += __shfl_xor(t3[1], off, 64);
        t3[2] += __shfl_xor(t3[2], off, 64);
    }
    if (lane == 0) {
        zacc[b*3 + 0] = t3[0];
        zacc[b*3 + 1] = t3[1];
        zacc[b*3 + 2] = t3[2];
    }
}

// =================== unit_repr (float4) ===================
__global__ __launch_bounds__(256) void unitrepr_kernel(const int* __restrict__ Aarr, const int* __restrict__ posa,
                                                       const int* __restrict__ Barr,
                                                       const float* __restrict__ atom_emb, const float* __restrict__ pos_emb,
                                                       const float* __restrict__ block_emb,
                                                       const float* __restrict__ hf, float* __restrict__ out_ur) {
    int gid = blockIdx.x*256 + threadIdx.x;      // 32768 units x 128 threads
    int u = gid >> 7, c = (gid & 127) << 2, b = u >> 2;
    float4 va = *(const float4*)(atom_emb + (size_t)Aarr[u]*512 + c);
    float4 vp = *(const float4*)(pos_emb + (size_t)posa[u]*512 + c);
    float4 vb = *(const float4*)(block_emb + (size_t)Barr[b]*512 + c);
    float4 vh = *(const float4*)(hf + (size_t)b*512 + c);
    float4 o;
    o.x = va.x + vp.x + vb.x + vh.x;
    o.y = va.y + vp.y + vb.y + vh.y;
    o.z = va.z + vp.z + vb.z + vh.z;
    o.w = va.w + vp.w + vb.w + vh.w;
    *(float4*)(out_ur + (size_t)u*512 + c) = o;
}

extern "C" void kernel_launch(void* const* d_in, const int* in_sizes, int n_in,
                              void* d_out, int out_size, void* d_ws, size_t ws_size,
                              hipStream_t stream) {
    const float* Z         = (const float*)d_in[0];
    const int*   B         = (const int*)d_in[1];
    const int*   A         = (const int*)d_in[2];
    const int*   ap        = (const int*)d_in[3];
    const int*   seg       = (const int*)d_in[6];
    const float* noise     = (const float*)d_in[7];
    const int*   nl        = (const int*)d_in[8];
    const float* sig       = (const float*)d_in[9];
    const float* atom_emb  = (const float*)d_in[10];
    const float* pos_emb   = (const float*)d_in[11];
    const float* block_emb = (const float*)d_in[12];
    const float* edge_emb  = (const float*)d_in[13];
    const float* Wm        = (const float*)d_in[14];
    const float* We        = (const float*)d_in[15];
    const float* Wu        = (const float*)d_in[16];
    const float* wz        = (const float*)d_in[17];
    const float* W1        = (const float*)d_in[18];
    const float* b1        = (const float*)d_in[19];
    const float* W2        = (const float*)d_in[20];
    (void)in_sizes; (void)n_in; (void)d_ws; (void)ws_size; (void)out_size;

    float* out = (float*)d_out;
    const size_t o1 = 8, o2 = 98312, o3 = 16875528, o4 = 21069832, o5 = 21073928;
    float* out_e    = out;
    float* out_pn   = out + o1;
    float* out_ur   = out + o2;
    float* hf       = out + o3;   // block_repr == final h (fp32), updated in place
    float* out_gr   = out + o4;
    float* out_loss = out + o5;

    // scratch arena inside the unit_repr output region (67 MB); unit_repr written last
    char* arena = (char*)(out + o2);
    bf16*  Pb   = (bf16*)(arena);                  // 8 MB
    bf16*  msum = (bf16*)(arena + 16777216);       // 8 MB
    bf16*  sh   = (bf16*)(arena + 25165824);       // 8 MB
    bf16*  hb   = (bf16*)(arena + 33554432);       // 8 MB
    float* Zp   = (float*)(arena + 41943040);
    float* Zb0  = (float*)(arena + 42336256);
    float* Zb   = (float*)(arena + 42434560);
    float* zacc = (float*)(arena + 42532864);
    int*   nbr  = (int*)  (arena + 42631168);
    bf16*  WmT  = (bf16*) (arena + 43220992);
    bf16*  WuT  = (bf16*) (arena + 44793856);
    bf16*  W1T  = (bf16*) (arena + 46366720);
    float* ebias= (float*)(arena + 46891008);

    init_kernel<<<8192 + 256, 256, 0, stream>>>(
        Z, noise, nl, sig, A, ap, B, atom_emb, pos_emb, block_emb,
        Wm, Zp, Zb0, Zb, hf, hb, WmT);

    knn_pgemm0_kernel<<<512 + 2048 + 1536 + 12 + 17, 256, 0, stream>>>(
        hb, WmT, Pb, Zp, seg, nbr,
        Wm, Wu, W1, WmT, WuT, W1T,
        edge_emb, We, ebias, out_gr, out_e, out_loss);

    for (int l = 0; l < 3; l++) {
        if (l > 0)
            wgemm_kernel<0><<<1024, 256, 0, stream>>>(hb, WmT + (size_t)l*262144, Pb,
                                                 nullptr, nullptr, nullptr, nullptr, nullptr, nullptr,
                                                 nullptr, nullptr, nullptr, nullptr, nullptr, nullptr, nullptr);
        edge_kernel<<<2048, 256, 0, stream>>>(Pb, ebias + l*1024, wz + l*512, Zb, nbr, msum, zacc);
        wgemm_kernel<1><<<1024, 256, 0, stream>>>(msum, WuT + (size_t)l*262144, nullptr,
                                             hf, hb, (l == 2) ? sh : nullptr, nullptr, nullptr, nullptr,
                                             Zb, zacc, Zb0, noise, out_pn, out_loss, out_gr);
    }
    wgemm_kernel<2><<<1024, 256, 0, stream>>>(sh, W1T, nullptr, nullptr, nullptr, nullptr,
                                         b1, W2, out_e, nullptr, nullptr,
                                         nullptr, nullptr, nullptr, nullptr, nullptr);
    // unit_repr last: overwrites the scratch arena
    unitrepr_kernel<<<16384, 256, 0, stream>>>(A, ap, B, atom_emb, pos_emb, block_emb, hf, out_ur);
}

// Round 11
// 461.800 us; speedup vs baseline: 1.2386x; 1.2386x over previous
//
#include <hip/hip_runtime.h>
#include <hip/hip_bf16.h>

typedef __bf16 bf16;
typedef __bf16 bf16x2 __attribute__((ext_vector_type(2)));
typedef __bf16 bf16x8 __attribute__((ext_vector_type(8)));
typedef float floatx4 __attribute__((ext_vector_type(4)));
typedef float floatx2 __attribute__((ext_vector_type(2)));

__device__ __forceinline__ float silu_f(float x) {
    float e = __expf(-x);
    return x * __builtin_amdgcn_rcpf(1.0f + e);
}

__device__ __forceinline__ float2 unpack_bf2(unsigned v) {
    float2 r;
    r.x = __uint_as_float(v << 16);
    r.y = __uint_as_float(v & 0xFFFF0000u);
    return r;
}

// 8 bf16 -> 8 f32 via bit ops (2 VALU per pair)
__device__ __forceinline__ void unpack8(const bf16* p, float* o) {
    uint4 u = *(const uint4*)p;
    float2 a = unpack_bf2(u.x); o[0]=a.x; o[1]=a.y;
    float2 b = unpack_bf2(u.y); o[2]=b.x; o[3]=b.y;
    float2 c = unpack_bf2(u.z); o[4]=c.x; o[5]=c.y;
    float2 d = unpack_bf2(u.w); o[6]=d.x; o[7]=d.y;
}

// async global -> LDS, 16B per lane; lds dest = wave-uniform base + lane*16 (HW rule)
__device__ __forceinline__ void gll16(const bf16* g, bf16* l) {
    __builtin_amdgcn_global_load_lds((const __attribute__((address_space(1))) void*)g,
                                     (__attribute__((address_space(3))) void*)l, 16, 0, 0);
}

// =================== init: setup (Zp/Zb/h) + WmT(l=0) transpose only ===================
__global__ __launch_bounds__(256) void init_kernel(
    const float* __restrict__ Z, const float* __restrict__ noise,
    const int* __restrict__ nl, const float* __restrict__ sig,
    const int* __restrict__ Aarr, const int* __restrict__ posa, const int* __restrict__ Barr,
    const float* __restrict__ atom_emb, const float* __restrict__ pos_emb,
    const float* __restrict__ block_emb,
    const float* __restrict__ Wm,
    float* __restrict__ Zp, float* __restrict__ Zb0, float* __restrict__ Zb,
    float* __restrict__ hf, bf16* __restrict__ hb,
    bf16* __restrict__ WmT)
{
    __shared__ float zsh[12];
    __shared__ float tile[32][33];
    int bid = blockIdx.x, tid = threadIdx.x;
    if (bid < 8192) {
        int b = bid, g = b >> 10;
        if (tid < 12) {
            float sg = sig[nl[g]];
            int idx = b*12 + tid;
            float zp = Z[idx] + noise[idx]*sg;
            Zp[idx] = zp;
            zsh[tid] = zp;
        }
        __syncthreads();
        if (tid < 3) {
            float v = 0.25f*(zsh[tid] + zsh[3+tid] + zsh[6+tid] + zsh[9+tid]);
            Zb0[b*3+tid] = v; Zb[b*3+tid] = v;
        }
        int ai[4], pi[4];
        #pragma unroll
        for (int a = 0; a < 4; a++) { ai[a] = Aarr[b*4+a]*512; pi[a] = posa[b*4+a]*512; }
        int bb = Barr[b]*512;
        #pragma unroll
        for (int cc = 0; cc < 2; cc++) {
            int c = tid + cc*256;
            float s = 0.0f;
            #pragma unroll
            for (int a = 0; a < 4; a++) s += atom_emb[ai[a]+c] + pos_emb[pi[a]+c];
            s = 0.25f*s + block_emb[bb+c];
            hf[(size_t)b*512+c] = s;
            hb[(size_t)b*512+c] = (bf16)s;
        }
        return;
    }
    // WmT layer-0 transpose (needed by knn_pgemm0 itself): 256 tiles of 32x32
    int rem = bid - 8192;
    int bx = rem & 15, by = rem >> 4;
    int tx = tid & 31, ty = tid >> 5;     // 32 x 8
    #pragma unroll
    for (int i = 0; i < 32; i += 8)
        tile[ty+i][tx] = Wm[(size_t)(by*32+ty+i)*512 + bx*32+tx];
    __syncthreads();
    #pragma unroll
    for (int i = 0; i < 32; i += 8)
        WmT[(size_t)(bx*32+ty+i)*512 + by*32+tx] = (bf16)tile[tx][ty+i];
}

// =================== KNN body: one wave per dst block; packed-fp32 distances ===================
__device__ void knn_body(int kb, const float* __restrict__ Zp, const int* __restrict__ seg,
                         int* __restrict__ nbr) {
    int wid = threadIdx.x >> 6;
    int lane = threadIdx.x & 63;
    int r = ((kb & 7) << 10) + ((kb >> 3) << 2) + wid;   // XCD-local graph
    int g = r >> 10;
    int il = r & 1023;
    int base = g << 10;
    int segr = seg[r];
    float za[4][3];
    #pragma unroll
    for (int a = 0; a < 4; a++)
        #pragma unroll
        for (int d = 0; d < 3; d++)
            za[a][d] = Zp[r*12 + a*3 + d];
    floatx2 ax[4], ay[4], az[4];
    #pragma unroll
    for (int a = 0; a < 4; a++) {
        ax[a] = (floatx2){za[a][0], za[a][0]};
        ay[a] = (floatx2){za[a][1], za[a][1]};
        az[a] = (floatx2){za[a][2], za[a][2]};
    }
    float dist[16];
    unsigned smask = 0;
    #pragma unroll
    for (int t = 0; t < 16; t++) {
        int jb = base + t*64 + lane;
        const float4* p = (const float4*)(Zp + (size_t)jb*12);
        float4 v0 = p[0], v1 = p[1], v2 = p[2];
        floatx2 bx0 = {v0.x, v0.w}, by0 = {v0.y, v1.x}, bz0 = {v0.z, v1.y};
        floatx2 bx1 = {v1.z, v2.y}, by1 = {v1.w, v2.z}, bz1 = {v2.x, v2.w};
        floatx2 mn = {3.0e38f, 3.0e38f};
        #pragma unroll
        for (int a = 0; a < 4; a++) {
            floatx2 dx = ax[a] - bx0, dy = ay[a] - by0, dz = az[a] - bz0;
            floatx2 dd = dx*dx + dy*dy + dz*dz;      // v_pk_mul/fma_f32
            mn.x = fminf(mn.x, dd.x); mn.y = fminf(mn.y, dd.y);
            dx = ax[a] - bx1; dy = ay[a] - by1; dz = az[a] - bz1;
            dd = dx*dx + dy*dy + dz*dz;
            mn.x = fminf(mn.x, dd.x); mn.y = fminf(mn.y, dd.y);
        }
        dist[t] = fminf(mn.x, mn.y);
        if (seg[jb] == segr) smask |= (1u << t);
    }
    const float INF = 3.0e38f;
    for (int phase = 0; phase < 2; phase++) {
        float wd[16];
        #pragma unroll
        for (int t = 0; t < 16; t++) {
            bool ok = (phase == 0) ? (((smask >> t) & 1u) && (t*64 + lane != il))
                                   : (!((smask >> t) & 1u));
            wd[t] = ok ? dist[t] : INF;
        }
        for (int it = 0; it < 9; it++) {
            float bd = wd[0]; int bt = 0;
            #pragma unroll
            for (int t = 1; t < 16; t++) { if (wd[t] < bd) { bd = wd[t]; bt = t; } }
            float mv = bd;
            #pragma unroll
            for (int off = 32; off >= 1; off >>= 1) mv = fminf(mv, __shfl_xor(mv, off, 64));
            unsigned long long msk = __ballot(bd == mv);
            int wl = __ffsll(msk) - 1;
            int wt = __shfl(bt, wl, 64);
            if (lane == 0) nbr[r*18 + phase*9 + it] = base + wt*64 + wl;
            bool amwin = (lane == wl);
            #pragma unroll
            for (int t = 0; t < 16; t++) if (amwin && t == wt) wd[t] = INF;
        }
    }
}

// =================== block GEMM (mode-0 only): 128x64 tile, LDS staging (fused kernel) ===================
__device__ void gemm0_body(const bf16* __restrict__ A, const bf16* __restrict__ BT,
                           bf16* __restrict__ Pb, int bid)
{
    __shared__ alignas(16) bf16 sA[128*32];
    __shared__ alignas(16) bf16 sB[64*32];
    int mt = bid & 63, nt = bid >> 6;
    int m0 = mt*128, n0 = nt*64;
    int tid = threadIdx.x, lane = tid & 63, w = tid >> 6;
    int wm = w & 1, wn = w >> 1;
    int lm = lane & 15, q = lane >> 4;

    int pA0 = w*128 + lane, pA1 = pA0 + 64, pB = w*64 + lane;
    int rA0 = pA0 >> 2, qA0 = (pA0 & 3) ^ ((rA0 >> 1) & 3);
    int rA1 = pA1 >> 2, qA1 = (pA1 & 3) ^ ((rA1 >> 1) & 3);
    int rB  = pB  >> 2, qB  = (pB  & 3) ^ ((rB  >> 1) & 3);
    const bf16* gA0 = A  + (size_t)(m0 + rA0)*512 + qA0*8;
    const bf16* gA1 = A  + (size_t)(m0 + rA1)*512 + qA1*8;
    const bf16* gB  = BT + (size_t)(n0 + rB )*512 + qB*8;
    int dA0 = (w*128)*8, dA1 = (w*128 + 64)*8, dB = (w*64)*8;

    int swq = (q ^ ((lm >> 1) & 3)) * 8;
    int offA[4], offB[2];
    #pragma unroll
    for (int tm = 0; tm < 4; tm++) offA[tm] = (wm*64 + tm*16 + lm)*32 + swq;
    #pragma unroll
    for (int tn = 0; tn < 2; tn++) offB[tn] = (wn*32 + tn*16 + lm)*32 + swq;

    floatx4 zv = {0.0f, 0.0f, 0.0f, 0.0f};
    floatx4 acc[4][2];
    #pragma unroll
    for (int i = 0; i < 4; i++)
        #pragma unroll
        for (int j = 0; j < 2; j++) acc[i][j] = zv;

    for (int k0 = 0; k0 < 512; k0 += 32) {
        gll16(gA0 + k0, sA + dA0);
        gll16(gA1 + k0, sA + dA1);
        gll16(gB  + k0, sB + dB);
        __syncthreads();
        bf16x8 af[4], bfr[2];
        #pragma unroll
        for (int tm = 0; tm < 4; tm++) af[tm] = *(const bf16x8*)(sA + offA[tm]);
        #pragma unroll
        for (int tn = 0; tn < 2; tn++) bfr[tn] = *(const bf16x8*)(sB + offB[tn]);
        #pragma unroll
        for (int tm = 0; tm < 4; tm++)
            #pragma unroll
            for (int tn = 0; tn < 2; tn++)
                acc[tm][tn] = __builtin_amdgcn_mfma_f32_16x16x32_bf16(af[tm], bfr[tn], acc[tm][tn], 0, 0, 0);
        __syncthreads();
    }

    #pragma unroll
    for (int tm = 0; tm < 4; tm++)
        #pragma unroll
        for (int tn = 0; tn < 2; tn++)
            #pragma unroll
            for (int rr = 0; rr < 4; rr++) {
                int row = m0 + wm*64 + tm*16 + q*4 + rr;
                int col = n0 + wn*32 + tn*16 + lm;
                Pb[(size_t)row*512 + col] = (bf16)acc[tm][tn][rr];
            }
}

// =================== standalone GEMM: wave-private LDS staging, NO barriers in K-loop ===================
// Block = 128x64 tile (512 blocks). Wave w owns rows m0+w*32..+31 x cols n0..n0+63.
// Each wave double-buffers its own A(32x32) + B(64x32) in private LDS (12 KB/wave, 48 KB/block,
// 3 blocks/CU = 12 independent wave-chains/CU). Counted vmcnt(6) per tile (6 gll16/tile).
// mode 0: Pb = bf16(acc)
// mode 1: hf += silu(acc); hb (l<2) or shp (l==2); nt==0 folds Zb += zacc/18;
//         l==2 additionally folds graph_repr (atomics) and (nt==0) pred_noise + loss
// mode 2: t = silu(acc + b1[col]); out_e[g] += sum(t . W2) (one atomic per wave)
template<int MODE>
__global__ __launch_bounds__(256) void gemm_mode_kernel(
    const bf16* __restrict__ A, const bf16* __restrict__ BT,
    bf16* __restrict__ Pb, float* __restrict__ hf,
    bf16* __restrict__ hb, bf16* __restrict__ shp,
    const float* __restrict__ b1, const float* __restrict__ W2,
    float* __restrict__ out_e,
    float* __restrict__ Zb, const float* __restrict__ zacc,
    const float* __restrict__ Zb0, const float* __restrict__ noise,
    float* __restrict__ out_pn, float* __restrict__ out_loss,
    float* __restrict__ out_gr)
{
    __shared__ alignas(16) bf16 sAw[4][2][1024];   // [wave][buf][32 rows x 32 k]
    __shared__ alignas(16) bf16 sBw[4][2][2048];   // [wave][buf][64 rows x 32 k]
    __shared__ float lsh[4];
    int bid = blockIdx.x;
    int mt = bid & 63, nt = bid >> 6;
    int m0 = mt*128, n0 = nt*64;
    int tid = threadIdx.x, lane = tid & 63, w = tid >> 6;
    int lm = lane & 15, q = lane >> 4;
    int r0 = m0 + w*32;

    // staging sources (XOR chunk swizzle: physical chunk p -> row p>>2, chunk (p&3)^((row>>1)&3))
    const bf16* gA[2]; const bf16* gB[4];
    #pragma unroll
    for (int j = 0; j < 2; j++) {
        int p = j*64 + lane;
        int r = p >> 2, qc = (p & 3) ^ ((r >> 1) & 3);
        gA[j] = A + (size_t)(r0 + r)*512 + qc*8;
    }
    #pragma unroll
    for (int j = 0; j < 4; j++) {
        int p = j*64 + lane;
        int r = p >> 2, qc = (p & 3) ^ ((r >> 1) & 3);
        gB[j] = BT + (size_t)(n0 + r)*512 + qc*8;
    }

    // fragment read offsets (swizzle depends only on lm)
    int swq = (q ^ ((lm >> 1) & 3)) * 8;
    int offA[2], offB[4];
    #pragma unroll
    for (int tm = 0; tm < 2; tm++) offA[tm] = (tm*16 + lm)*32 + swq;
    #pragma unroll
    for (int tn = 0; tn < 4; tn++) offB[tn] = (tn*16 + lm)*32 + swq;

    floatx4 zv = {0.0f, 0.0f, 0.0f, 0.0f};
    floatx4 acc[2][4];
    #pragma unroll
    for (int i = 0; i < 2; i++)
        #pragma unroll
        for (int j = 0; j < 4; j++) acc[i][j] = zv;

    // prologue: stage tile 0 into buf 0 (6 loads in flight)
    #pragma unroll
    for (int j = 0; j < 2; j++) gll16(gA[j], &sAw[w][0][j*512]);
    #pragma unroll
    for (int j = 0; j < 4; j++) gll16(gB[j], &sBw[w][0][j*512]);
    #pragma unroll
    for (int t = 0; t < 16; t++) {
        const int cur = t & 1;
        if (t < 15) {
            const int k0 = (t + 1) * 32;
            const int nb = cur ^ 1;
            #pragma unroll
            for (int j = 0; j < 2; j++) gll16(gA[j] + k0, &sAw[w][nb][j*512]);
            #pragma unroll
            for (int j = 0; j < 4; j++) gll16(gB[j] + k0, &sBw[w][nb][j*512]);
            asm volatile("s_waitcnt vmcnt(6)" ::: "memory");   // tile t landed; t+1 in flight
        } else {
            asm volatile("s_waitcnt vmcnt(0)" ::: "memory");   // tile 15 landed
        }
        // wave-private buffers: no barrier needed
        const bf16* aB = &sAw[w][cur][0];
        const bf16* bB = &sBw[w][cur][0];
        bf16x8 af[2], bfr[4];
        #pragma unroll
        for (int tm = 0; tm < 2; tm++) af[tm] = *(const bf16x8*)(aB + offA[tm]);
        #pragma unroll
        for (int tn = 0; tn < 4; tn++) bfr[tn] = *(const bf16x8*)(bB + offB[tn]);
        #pragma unroll
        for (int tm = 0; tm < 2; tm++)
            #pragma unroll
            for (int tn = 0; tn < 4; tn++)
                acc[tm][tn] = __builtin_amdgcn_mfma_f32_16x16x32_bf16(af[tm], bfr[tn], acc[tm][tn], 0, 0, 0);
    }

    if (MODE == 2) {
        float esum = 0.0f;
        #pragma unroll
        for (int tn = 0; tn < 4; tn++) {
            int col = n0 + tn*16 + lm;
            float bb = b1[col];
            float w2 = W2[col];
            #pragma unroll
            for (int tm = 0; tm < 2; tm++)
                #pragma unroll
                for (int rr = 0; rr < 4; rr++)
                    esum += silu_f(acc[tm][tn][rr] + bb) * w2;
        }
        #pragma unroll
        for (int off = 32; off >= 1; off >>= 1) esum += __shfl_xor(esum, off, 64);
        if (lane == 0) atomicAdd(&out_e[m0 >> 10], esum);
        return;
    }

    if (MODE == 1 && nt == 0) {       // fold zb_apply: rows m0..m0+127 (block-wide)
        int o = m0*3 + tid;
        Zb[o] += zacc[o] * (1.0f/18.0f);
        if (tid < 128) {
            int o2 = m0*3 + 256 + tid;
            Zb[o2] += zacc[o2] * (1.0f/18.0f);
        }
    }

    float colsum[4] = {0.0f, 0.0f, 0.0f, 0.0f};
    #pragma unroll
    for (int tm = 0; tm < 2; tm++) {
        #pragma unroll
        for (int tn = 0; tn < 4; tn++) {
            #pragma unroll
            for (int rr = 0; rr < 4; rr++) {
                int row = r0 + tm*16 + q*4 + rr;
                int col = n0 + tn*16 + lm;
                size_t o = (size_t)row*512 + col;
                float v = acc[tm][tn][rr];
                if (MODE == 0) {
                    Pb[o] = (bf16)v;
                } else {
                    float nh = hf[o] + silu_f(v);
                    hf[o] = nh;
                    colsum[tn] += nh;
                    if (shp) shp[o] = (bf16)silu_f(nh);   // l==2: hb dead, sh needed
                    else     hb[o] = (bf16)nh;            // l<2: hb feeds next pgemm
                }
            }
        }
    }

    if (MODE == 1 && shp) {           // l==2 fold: graph_repr + pred_noise + loss
        int g = m0 >> 10;
        #pragma unroll
        for (int tn = 0; tn < 4; tn++) {
            float v = colsum[tn];
            v += __shfl_xor(v, 16, 64);
            v += __shfl_xor(v, 32, 64);
            if (q == 0) atomicAdd(&out_gr[g*512 + n0 + tn*16 + lm], v);
        }
        if (nt == 0) {
            __syncthreads();          // zb fold (all threads) visible before Zb re-read
            float per2 = 0.0f;
            #pragma unroll
            for (int j = 0; j < 2; j++) {
                int u = m0*4 + tid*2 + j;
                int b = u >> 2;
                #pragma unroll
                for (int d = 0; d < 3; d++) {
                    float dv = Zb[b*3 + d] - Zb0[b*3 + d];
                    out_pn[(size_t)u*3 + d] = dv;
                    float e = dv - noise[(size_t)u*3 + d];
                    per2 += e*e;
                }
            }
            #pragma unroll
            for (int off = 32; off >= 1; off >>= 1) per2 += __shfl_xor(per2, off, 64);
            if (lane == 0) lsh[w] = per2;
            __syncthreads();
            if (tid == 0)
                atomicAdd(out_loss, (lsh[0]+lsh[1]+lsh[2]+lsh[3]) * (1.0f/16.0f));
        }
    }
}

// fused: [0,512) P-GEMM layer 0; [512,2560) KNN; [2560,4096) transposes l>0;
//        [4096,4108) ebias; [4108,4125) output zeroing
__global__ __launch_bounds__(256) void knn_pgemm0_kernel(const bf16* __restrict__ hb,
                                                         const bf16* __restrict__ WmT,
                                                         bf16* __restrict__ Pb,
                                                         const float* __restrict__ Zp,
                                                         const int* __restrict__ seg,
                                                         int* __restrict__ nbr,
                                                         const float* __restrict__ Wm,
                                                         const float* __restrict__ Wu,
                                                         const float* __restrict__ W1,
                                                         bf16* __restrict__ WmTw,
                                                         bf16* __restrict__ WuT,
                                                         bf16* __restrict__ W1T,
                                                         const float* __restrict__ edge_emb,
                                                         const float* __restrict__ We,
                                                         float* __restrict__ ebias,
                                                         float* __restrict__ out_gr,
                                                         float* __restrict__ out_e,
                                                         float* __restrict__ out_loss) {
    __shared__ float ttile[32][33];
    int bid = blockIdx.x, tid = threadIdx.x;
    if (bid < 512) {
        gemm0_body(hb, WmT, Pb, bid);
        return;
    }
    if (bid < 2560) {
        knn_body(bid - 512, Zp, seg, nbr);
        return;
    }
    int tb = bid - 2560;
    if (tb < 1536) {   // 6 matrices (Wm l=1,2; Wu l=0..2; W1) x 256 tiles
        int z = 1 + (tb >> 8), rem = tb & 255;
        int bx = rem & 15, by = rem >> 4;
        int tx = tid & 31, ty = tid >> 5;     // 32 x 8
        const float* src; bf16* dst;
        if (z < 3)      { src = Wm + (size_t)z*262144;     dst = WmTw + (size_t)z*262144; }
        else if (z < 6) { src = Wu + (size_t)(z-3)*262144; dst = WuT + (size_t)(z-3)*262144; }
        else            { src = W1;                        dst = W1T; }
        #pragma unroll
        for (int i = 0; i < 32; i += 8)
            ttile[ty+i][tx] = src[(size_t)(by*32+ty+i)*512 + bx*32+tx];
        __syncthreads();
        #pragma unroll
        for (int i = 0; i < 32; i += 8)
            dst[(size_t)(bx*32+ty+i)*512 + by*32+tx] = (bf16)ttile[tx][ty+i];
        return;
    }
    tb -= 1536;
    if (tb < 12) {
        int gid = tb*256 + tid;
        int l = gid >> 10, t = (gid >> 9) & 1, c = gid & 511;
        float s = 0.0f;
        #pragma unroll 8
        for (int e = 0; e < 64; e++)
            s += edge_emb[t*64 + e] * We[(size_t)(l*64 + e)*512 + c];
        ebias[gid] = s;
        return;
    }
    tb -= 12;
    int k = tb*256 + tid;
    if (k < 4096) out_gr[k] = 0.0f;
    else if (k < 4104) out_e[k-4096] = 0.0f;
    else if (k == 4104) out_loss[0] = 0.0f;
}

// =================== edge aggregation: one WAVE per dst block, 8 ch/lane ===================
__global__ __launch_bounds__(256) void edge_kernel(const bf16* __restrict__ Pb, const float* __restrict__ ebias,
                                                   const float* __restrict__ wz, const float* __restrict__ Zb,
                                                   const int* __restrict__ nbr, bf16* __restrict__ msum,
                                                   float* __restrict__ zacc) {
    int bid = blockIdx.x, tid = threadIdx.x;
    int lane = tid & 63, wid = tid >> 6;
    int b = ((bid & 7) << 10) | ((bid >> 3) << 2) | wid;   // XCD-local graph, 4 dst blocks/block
    __shared__ int srcs[4][18];
    if (tid < 72) {
        int w2 = tid / 18, e2 = tid - w2*18;
        int bb = ((bid & 7) << 10) | ((bid >> 3) << 2) | w2;
        srcs[w2][e2] = nbr[bb*18 + e2];
    }
    __syncthreads();
    int c0 = lane << 3;     // 8 channels per lane
    float pd[8], eb0[8], eb1[8], wv[8];
    unpack8(Pb + (size_t)b*512 + c0, pd);
    *(float4*)(eb0)   = *(const float4*)(ebias + c0);
    *(float4*)(eb0+4) = *(const float4*)(ebias + c0 + 4);
    *(float4*)(eb1)   = *(const float4*)(ebias + 512 + c0);
    *(float4*)(eb1+4) = *(const float4*)(ebias + 512 + c0 + 4);
    *(float4*)(wv)    = *(const float4*)(wz + c0);
    *(float4*)(wv+4)  = *(const float4*)(wz + c0 + 4);
    float ms[8];
    #pragma unroll
    for (int j = 0; j < 8; j++) ms[j] = 0.0f;
    float pdot[18];
    #pragma unroll
    for (int e = 0; e < 18; e++) {
        int s = srcs[wid][e];
        float pv[8];
        unpack8(Pb + (size_t)s*512 + c0, pv);
        float dot = 0.0f;
        #pragma unroll
        for (int j = 0; j < 8; j++) {
            float base = (e < 9) ? eb0[j] : eb1[j];     // e compile-time after unroll
            float m = silu_f(pv[j] + pd[j] + base);
            ms[j] += m;
            dot += m * wv[j];
        }
        pdot[e] = dot;
    }
    bf16x8 mp;
    #pragma unroll
    for (int j = 0; j < 8; j++) mp[j] = (bf16)ms[j];
    *(bf16x8*)(msum + (size_t)b*512 + c0) = mp;
    // wave-reduce each pdot[e] (butterfly -> every lane has full sum)
    #pragma unroll
    for (int e = 0; e < 18; e++) {
        float v = pdot[e];
        #pragma unroll
        for (int off = 32; off >= 1; off >>= 1) v += __shfl_xor(v, off, 64);
        pdot[e] = v;
    }
    // lane e takes edge e: select own dot, tanh, z-term; reduce 3 comps over lanes
    float dotv = 0.0f;
    #pragma unroll
    for (int e = 0; e < 18; e++) dotv = (lane == e) ? pdot[e] : dotv;
    float coef = tanhf(dotv);
    float t3[3] = {0.0f, 0.0f, 0.0f};
    if (lane < 18) {
        int se = srcs[wid][lane];
        #pragma unroll
        for (int d = 0; d < 3; d++)
            t3[d] = (Zb[se*3 + d] - Zb[b*3 + d]) * coef;
    }
    #pragma unroll
    for (int off = 16; off >= 1; off >>= 1) {
        t3[0] += __shfl_xor(t3[0], off, 64);
        t3[1] += __shfl_xor(t3[1], off, 64);
        t3[2] += __shfl_xor(t3[2], off, 64);
    }
    if (lane == 0) {
        zacc[b*3 + 0] = t3[0];
        zacc[b*3 + 1] = t3[1];
        zacc[b*3 + 2] = t3[2];
    }
}

// =================== unit_repr (float4) ===================
__global__ __launch_bounds__(256) void unitrepr_kernel(const int* __restrict__ Aarr, const int* __restrict__ posa,
                                                       const int* __restrict__ Barr,
                                                       const float* __restrict__ atom_emb, const float* __restrict__ pos_emb,
                                                       const float* __restrict__ block_emb,
                                                       const float* __restrict__ hf, float* __restrict__ out_ur) {
    int gid = blockIdx.x*256 + threadIdx.x;      // 32768 units x 128 threads
    int u = gid >> 7, c = (gid & 127) << 2, b = u >> 2;
    float4 va = *(const float4*)(atom_emb + (size_t)Aarr[u]*512 + c);
    float4 vp = *(const float4*)(pos_emb + (size_t)posa[u]*512 + c);
    float4 vb = *(const float4*)(block_emb + (size_t)Barr[b]*512 + c);
    float4 vh = *(const float4*)(hf + (size_t)b*512 + c);
    float4 o;
    o.x = va.x + vp.x + vb.x + vh.x;
    o.y = va.y + vp.y + vb.y + vh.y;
    o.z = va.z + vp.z + vb.z + vh.z;
    o.w = va.w + vp.w + vb.w + vh.w;
    *(float4*)(out_ur + (size_t)u*512 + c) = o;
}

extern "C" void kernel_launch(void* const* d_in, const int* in_sizes, int n_in,
                              void* d_out, int out_size, void* d_ws, size_t ws_size,
                              hipStream_t stream) {
    const float* Z         = (const float*)d_in[0];
    const int*   B         = (const int*)d_in[1];
    const int*   A         = (const int*)d_in[2];
    const int*   ap        = (const int*)d_in[3];
    const int*   seg       = (const int*)d_in[6];
    const float* noise     = (const float*)d_in[7];
    const int*   nl        = (const int*)d_in[8];
    const float* sig       = (const float*)d_in[9];
    const float* atom_emb  = (const float*)d_in[10];
    const float* pos_emb   = (const float*)d_in[11];
    const float* block_emb = (const float*)d_in[12];
    const float* edge_emb  = (const float*)d_in[13];
    const float* Wm        = (const float*)d_in[14];
    const float* We        = (const float*)d_in[15];
    const float* Wu        = (const float*)d_in[16];
    const float* wz        = (const float*)d_in[17];
    const float* W1        = (const float*)d_in[18];
    const float* b1        = (const float*)d_in[19];
    const float* W2        = (const float*)d_in[20];
    (void)in_sizes; (void)n_in; (void)d_ws; (void)ws_size; (void)out_size;

    float* out = (float*)d_out;
    const size_t o1 = 8, o2 = 98312, o3 = 16875528, o4 = 21069832, o5 = 21073928;
    float* out_e    = out;
    float* out_pn   = out + o1;
    float* out_ur   = out + o2;
    float* hf       = out + o3;   // block_repr == final h (fp32), updated in place
    float* out_gr   = out + o4;
    float* out_loss = out + o5;

    // scratch arena inside the unit_repr output region (67 MB); unit_repr written last
    char* arena = (char*)(out + o2);
    bf16*  Pb   = (bf16*)(arena);                  // 8 MB
    bf16*  msum = (bf16*)(arena + 16777216);       // 8 MB
    bf16*  sh   = (bf16*)(arena + 25165824);       // 8 MB
    bf16*  hb   = (bf16*)(arena + 33554432);       // 8 MB
    float* Zp   = (float*)(arena + 41943040);
    float* Zb0  = (float*)(arena + 42336256);
    float* Zb   = (float*)(arena + 42434560);
    float* zacc = (float*)(arena + 42532864);
    int*   nbr  = (int*)  (arena + 42631168);
    bf16*  WmT  = (bf16*) (arena + 43220992);
    bf16*  WuT  = (bf16*) (arena + 44793856);
    bf16*  W1T  = (bf16*) (arena + 46366720);
    float* ebias= (float*)(arena + 46891008);

    init_kernel<<<8192 + 256, 256, 0, stream>>>(
        Z, noise, nl, sig, A, ap, B, atom_emb, pos_emb, block_emb,
        Wm, Zp, Zb0, Zb, hf, hb, WmT);

    knn_pgemm0_kernel<<<512 + 2048 + 1536 + 12 + 17, 256, 0, stream>>>(
        hb, WmT, Pb, Zp, seg, nbr,
        Wm, Wu, W1, WmT, WuT, W1T,
        edge_emb, We, ebias, out_gr, out_e, out_loss);

    for (int l = 0; l < 3; l++) {
        if (l > 0)
            gemm_mode_kernel<0><<<512, 256, 0, stream>>>(hb, WmT + (size_t)l*262144, Pb,
                                                 nullptr, nullptr, nullptr, nullptr, nullptr, nullptr,
                                                 nullptr, nullptr, nullptr, nullptr, nullptr, nullptr, nullptr);
        edge_kernel<<<2048, 256, 0, stream>>>(Pb, ebias + l*1024, wz + l*512, Zb, nbr, msum, zacc);
        gemm_mode_kernel<1><<<512, 256, 0, stream>>>(msum, WuT + (size_t)l*262144, nullptr,
                                             hf, hb, (l == 2) ? sh : nullptr, nullptr, nullptr, nullptr,
                                             Zb, zacc, Zb0, noise, out_pn, out_loss, out_gr);
    }
    gemm_mode_kernel<2><<<512, 256, 0, stream>>>(sh, W1T, nullptr, nullptr, nullptr, nullptr,
                                         b1, W2, out_e, nullptr, nullptr,
                                         nullptr, nullptr, nullptr, nullptr, nullptr);
    // unit_repr last: overwrites the scratch arena
    unitrepr_kernel<<<16384, 256, 0, stream>>>(A, ap, B, atom_emb, pos_emb, block_emb, hf, out_ur);
}

// Round 13
// 427.054 us; speedup vs baseline: 1.3394x; 1.0814x over previous
//
#include <hip/hip_runtime.h>
#include <hip/hip_bf16.h>

typedef __bf16 bf16;
typedef __bf16 bf16x2 __attribute__((ext_vector_type(2)));
typedef __bf16 bf16x8 __attribute__((ext_vector_type(8)));
typedef float floatx4 __attribute__((ext_vector_type(4)));
typedef float floatx2 __attribute__((ext_vector_type(2)));

__device__ __forceinline__ float silu_f(float x) {
    float e = __expf(-x);
    return x * __builtin_amdgcn_rcpf(1.0f + e);
}

__device__ __forceinline__ float2 unpack_bf2(unsigned v) {
    float2 r;
    r.x = __uint_as_float(v << 16);
    r.y = __uint_as_float(v & 0xFFFF0000u);
    return r;
}

// 8 bf16 -> 8 f32 via bit ops (2 VALU per pair)
__device__ __forceinline__ void unpack8(const bf16* p, float* o) {
    uint4 u = *(const uint4*)p;
    float2 a = unpack_bf2(u.x); o[0]=a.x; o[1]=a.y;
    float2 b = unpack_bf2(u.y); o[2]=b.x; o[3]=b.y;
    float2 c = unpack_bf2(u.z); o[4]=c.x; o[5]=c.y;
    float2 d = unpack_bf2(u.w); o[6]=d.x; o[7]=d.y;
}

// async global -> LDS, 16B per lane; lds dest = base + lane*16 (HW rule)
__device__ __forceinline__ void gll16(const bf16* g, bf16* l) {
    __builtin_amdgcn_global_load_lds((const __attribute__((address_space(1))) void*)g,
                                     (__attribute__((address_space(3))) void*)l, 16, 0, 0);
}

// =================== init: setup (Zp/Zb/h) + WmT(l=0) transpose only ===================
__global__ __launch_bounds__(256) void init_kernel(
    const float* __restrict__ Z, const float* __restrict__ noise,
    const int* __restrict__ nl, const float* __restrict__ sig,
    const int* __restrict__ Aarr, const int* __restrict__ posa, const int* __restrict__ Barr,
    const float* __restrict__ atom_emb, const float* __restrict__ pos_emb,
    const float* __restrict__ block_emb,
    const float* __restrict__ Wm,
    float* __restrict__ Zp, float* __restrict__ Zb0, float* __restrict__ Zb,
    float* __restrict__ hf, bf16* __restrict__ hb,
    bf16* __restrict__ WmT)
{
    __shared__ float zsh[12];
    __shared__ float tile[32][33];
    int bid = blockIdx.x, tid = threadIdx.x;
    if (bid < 8192) {
        int b = bid, g = b >> 10;
        if (tid < 12) {
            float sg = sig[nl[g]];
            int idx = b*12 + tid;
            float zp = Z[idx] + noise[idx]*sg;
            Zp[idx] = zp;
            zsh[tid] = zp;
        }
        __syncthreads();
        if (tid < 3) {
            float v = 0.25f*(zsh[tid] + zsh[3+tid] + zsh[6+tid] + zsh[9+tid]);
            Zb0[b*3+tid] = v; Zb[b*3+tid] = v;
        }
        int ai[4], pi[4];
        #pragma unroll
        for (int a = 0; a < 4; a++) { ai[a] = Aarr[b*4+a]*512; pi[a] = posa[b*4+a]*512; }
        int bb = Barr[b]*512;
        #pragma unroll
        for (int cc = 0; cc < 2; cc++) {
            int c = tid + cc*256;
            float s = 0.0f;
            #pragma unroll
            for (int a = 0; a < 4; a++) s += atom_emb[ai[a]+c] + pos_emb[pi[a]+c];
            s = 0.25f*s + block_emb[bb+c];
            hf[(size_t)b*512+c] = s;
            hb[(size_t)b*512+c] = (bf16)s;
        }
        return;
    }
    // WmT layer-0 transpose (needed by knn_pgemm0 itself): 256 tiles of 32x32
    int rem = bid - 8192;
    int bx = rem & 15, by = rem >> 4;
    int tx = tid & 31, ty = tid >> 5;     // 32 x 8
    #pragma unroll
    for (int i = 0; i < 32; i += 8)
        tile[ty+i][tx] = Wm[(size_t)(by*32+ty+i)*512 + bx*32+tx];
    __syncthreads();
    #pragma unroll
    for (int i = 0; i < 32; i += 8)
        WmT[(size_t)(bx*32+ty+i)*512 + by*32+tx] = (bf16)tile[tx][ty+i];
}

// =================== KNN body: one wave per dst block; packed-fp32 distances ===================
__device__ void knn_body(int kb, const float* __restrict__ Zp, const int* __restrict__ seg,
                         int* __restrict__ nbr) {
    int wid = threadIdx.x >> 6;
    int lane = threadIdx.x & 63;
    int r = ((kb & 7) << 10) + ((kb >> 3) << 2) + wid;   // XCD-local graph
    int g = r >> 10;
    int il = r & 1023;
    int base = g << 10;
    int segr = seg[r];
    float za[4][3];
    #pragma unroll
    for (int a = 0; a < 4; a++)
        #pragma unroll
        for (int d = 0; d < 3; d++)
            za[a][d] = Zp[r*12 + a*3 + d];
    floatx2 ax[4], ay[4], az[4];
    #pragma unroll
    for (int a = 0; a < 4; a++) {
        ax[a] = (floatx2){za[a][0], za[a][0]};
        ay[a] = (floatx2){za[a][1], za[a][1]};
        az[a] = (floatx2){za[a][2], za[a][2]};
    }
    float dist[16];
    unsigned smask = 0;
    #pragma unroll
    for (int t = 0; t < 16; t++) {
        int jb = base + t*64 + lane;
        const float4* p = (const float4*)(Zp + (size_t)jb*12);
        float4 v0 = p[0], v1 = p[1], v2 = p[2];
        floatx2 bx0 = {v0.x, v0.w}, by0 = {v0.y, v1.x}, bz0 = {v0.z, v1.y};
        floatx2 bx1 = {v1.z, v2.y}, by1 = {v1.w, v2.z}, bz1 = {v2.x, v2.w};
        floatx2 mn = {3.0e38f, 3.0e38f};
        #pragma unroll
        for (int a = 0; a < 4; a++) {
            floatx2 dx = ax[a] - bx0, dy = ay[a] - by0, dz = az[a] - bz0;
            floatx2 dd = dx*dx + dy*dy + dz*dz;      // v_pk_mul/fma_f32
            mn.x = fminf(mn.x, dd.x); mn.y = fminf(mn.y, dd.y);
            dx = ax[a] - bx1; dy = ay[a] - by1; dz = az[a] - bz1;
            dd = dx*dx + dy*dy + dz*dz;
            mn.x = fminf(mn.x, dd.x); mn.y = fminf(mn.y, dd.y);
        }
        dist[t] = fminf(mn.x, mn.y);
        if (seg[jb] == segr) smask |= (1u << t);
    }
    const float INF = 3.0e38f;
    for (int phase = 0; phase < 2; phase++) {
        float wd[16];
        #pragma unroll
        for (int t = 0; t < 16; t++) {
            bool ok = (phase == 0) ? (((smask >> t) & 1u) && (t*64 + lane != il))
                                   : (!((smask >> t) & 1u));
            wd[t] = ok ? dist[t] : INF;
        }
        for (int it = 0; it < 9; it++) {
            float bd = wd[0]; int bt = 0;
            #pragma unroll
            for (int t = 1; t < 16; t++) { if (wd[t] < bd) { bd = wd[t]; bt = t; } }
            float mv = bd;
            #pragma unroll
            for (int off = 32; off >= 1; off >>= 1) mv = fminf(mv, __shfl_xor(mv, off, 64));
            unsigned long long msk = __ballot(bd == mv);
            int wl = __ffsll(msk) - 1;
            int wt = __shfl(bt, wl, 64);
            if (lane == 0) nbr[r*18 + phase*9 + it] = base + wt*64 + wl;
            bool amwin = (lane == wl);
            #pragma unroll
            for (int t = 0; t < 16; t++) if (amwin && t == wt) wd[t] = INF;
        }
    }
}

// =================== bf16 MFMA GEMM body: [8192,512] @ BT^T, tile 128x64, BK=32 ===================
// global_load_lds staging with XOR chunk swizzle; PIPE=1 adds depth-2 prefetch w/ counted vmcnt.
// mode 0: Pb = bf16(acc)
// mode 1: hf += silu(acc); hb = bf16(hf) (l<2) or shp = bf16(silu(hf)) (l==2, hb dead)
//         nt==0 tiles also apply Zb += zacc/18; l==2 additionally folds:
//         graph_repr column-sums (from registers) and (nt==0) pred_noise + loss
// mode 2: t = silu(acc + b1[col]); out_e[g] += sum(t . W2) (one atomic per block)
template<int PIPE>
__device__ void gemm_body(const bf16* __restrict__ A, const bf16* __restrict__ BT,
                          bf16* __restrict__ Pb, float* __restrict__ hf,
                          bf16* __restrict__ hb, bf16* __restrict__ shp,
                          const float* __restrict__ b1, const float* __restrict__ W2,
                          float* __restrict__ out_e,
                          float* __restrict__ Zb, const float* __restrict__ zacc,
                          const float* __restrict__ Zb0, const float* __restrict__ noise,
                          float* __restrict__ out_pn, float* __restrict__ out_loss,
                          float* __restrict__ out_gr,
                          int mode, int bid)
{
    constexpr int NBUF = PIPE ? 3 : 1;
    __shared__ alignas(16) bf16 sA[NBUF*128*32];
    __shared__ alignas(16) bf16 sB[NBUF*64*32];
    __shared__ float grbuf[4][32];
    __shared__ float lsh[4];
    __shared__ float ered[4];
    int mt = bid & 63, nt = bid >> 6;
    int m0 = mt*128, n0 = nt*64;
    int tid = threadIdx.x, lane = tid & 63, w = tid >> 6;
    int wm = w & 1, wn = w >> 1;
    int lm = lane & 15, q = lane >> 4;

    // staging: physical chunk p holds logical chunk (row=p>>2, qt=(p&3)^((row>>1)&3))
    int pA0 = w*128 + lane, pA1 = pA0 + 64, pB = w*64 + lane;
    int rA0 = pA0 >> 2, qA0 = (pA0 & 3) ^ ((rA0 >> 1) & 3);
    int rA1 = pA1 >> 2, qA1 = (pA1 & 3) ^ ((rA1 >> 1) & 3);
    int rB  = pB  >> 2, qB  = (pB  & 3) ^ ((rB  >> 1) & 3);
    const bf16* gA0 = A  + (size_t)(m0 + rA0)*512 + qA0*8;
    const bf16* gA1 = A  + (size_t)(m0 + rA1)*512 + qA1*8;
    const bf16* gB  = BT + (size_t)(n0 + rB )*512 + qB*8;
    int dA0 = (w*128)*8, dA1 = (w*128 + 64)*8, dB = (w*64)*8;

    // fragment read offsets (swizzle depends only on lm)
    int swq = (q ^ ((lm >> 1) & 3)) * 8;
    int offA[4], offB[2];
    #pragma unroll
    for (int tm = 0; tm < 4; tm++) offA[tm] = (wm*64 + tm*16 + lm)*32 + swq;
    #pragma unroll
    for (int tn = 0; tn < 2; tn++) offB[tn] = (wn*32 + tn*16 + lm)*32 + swq;

    floatx4 zv = {0.0f, 0.0f, 0.0f, 0.0f};
    floatx4 acc[4][2];
    #pragma unroll
    for (int i = 0; i < 4; i++)
        #pragma unroll
        for (int j = 0; j < 2; j++) acc[i][j] = zv;

    if constexpr (PIPE == 0) {
        for (int k0 = 0; k0 < 512; k0 += 32) {
            gll16(gA0 + k0, sA + dA0);
            gll16(gA1 + k0, sA + dA1);
            gll16(gB  + k0, sB + dB);
            __syncthreads();
            bf16x8 af[4], bfr[2];
            #pragma unroll
            for (int tm = 0; tm < 4; tm++) af[tm] = *(const bf16x8*)(sA + offA[tm]);
            #pragma unroll
            for (int tn = 0; tn < 2; tn++) bfr[tn] = *(const bf16x8*)(sB + offB[tn]);
            #pragma unroll
            for (int tm = 0; tm < 4; tm++)
                #pragma unroll
                for (int tn = 0; tn < 2; tn++)
                    acc[tm][tn] = __builtin_amdgcn_mfma_f32_16x16x32_bf16(af[tm], bfr[tn], acc[tm][tn], 0, 0, 0);
            __syncthreads();
        }
    } else {
        // prologue: stage tiles 0,1 into buffers 0,1 (6 loads in flight)
        gll16(gA0,      sA + dA0);
        gll16(gA1,      sA + dA1);
        gll16(gB,       sB + dB);
        gll16(gA0 + 32, sA + 4096 + dA0);
        gll16(gA1 + 32, sA + 4096 + dA1);
        gll16(gB  + 32, sB + 2048 + dB);
        #pragma unroll
        for (int t = 0; t < 16; t++) {
            const int cur = t % 3;
            if (t < 14) {
                const int k0 = (t + 2) * 32;
                const int nb = (t + 2) % 3;
                gll16(gA0 + k0, sA + nb*4096 + dA0);
                gll16(gA1 + k0, sA + nb*4096 + dA1);
                gll16(gB  + k0, sB + nb*2048 + dB);
                asm volatile("s_waitcnt vmcnt(6)" ::: "memory");   // tile t landed; t+1,t+2 in flight
            } else if (t == 14) {
                asm volatile("s_waitcnt vmcnt(3)" ::: "memory");   // tile 14 landed; 15 in flight
            } else {
                asm volatile("s_waitcnt vmcnt(0)" ::: "memory");   // tile 15 landed
            }
            __builtin_amdgcn_s_barrier();                          // all waves: tile t fully in LDS
            asm volatile("" ::: "memory");
            const bf16* a_ = sA + cur*4096;
            const bf16* b_ = sB + cur*2048;
            bf16x8 af[4], bfr[2];
            #pragma unroll
            for (int tm = 0; tm < 4; tm++) af[tm] = *(const bf16x8*)(a_ + offA[tm]);
            #pragma unroll
            for (int tn = 0; tn < 2; tn++) bfr[tn] = *(const bf16x8*)(b_ + offB[tn]);
            #pragma unroll
            for (int tm = 0; tm < 4; tm++)
                #pragma unroll
                for (int tn = 0; tn < 2; tn++)
                    acc[tm][tn] = __builtin_amdgcn_mfma_f32_16x16x32_bf16(af[tm], bfr[tn], acc[tm][tn], 0, 0, 0);
            asm volatile("" ::: "memory");
            __builtin_amdgcn_s_barrier();   // all waves consumed tile t; buffer reusable at iter t+1
        }
    }

    if (mode == 1 && nt == 0) {       // fold zb_apply: rows m0..m0+127
        int o = m0*3 + tid;
        Zb[o] += zacc[o] * (1.0f/18.0f);
        if (tid < 128) {
            int o2 = m0*3 + 256 + tid;
            Zb[o2] += zacc[o2] * (1.0f/18.0f);
        }
    }

    if (mode == 2) {
        float esum = 0.0f;
        #pragma unroll
        for (int tn = 0; tn < 2; tn++) {
            int col = n0 + wn*32 + tn*16 + lm;
            float bb = b1[col];
            float w2 = W2[col];
            #pragma unroll
            for (int tm = 0; tm < 4; tm++)
                #pragma unroll
                for (int rr = 0; rr < 4; rr++)
                    esum += silu_f(acc[tm][tn][rr] + bb) * w2;
        }
        #pragma unroll
        for (int off = 32; off >= 1; off >>= 1) esum += __shfl_xor(esum, off, 64);
        if (lane == 0) ered[w] = esum;
        __syncthreads();
        if (tid == 0) {
            float tot = ered[0] + ered[1] + ered[2] + ered[3];
            atomicAdd(&out_e[m0 >> 10], tot);   // all 128 rows of this block share one graph
        }
        return;
    }

    float colsum[2] = {0.0f, 0.0f};
    #pragma unroll
    for (int tm = 0; tm < 4; tm++) {
        #pragma unroll
        for (int tn = 0; tn < 2; tn++) {
            #pragma unroll
            for (int rr = 0; rr < 4; rr++) {
                int row = m0 + wm*64 + tm*16 + q*4 + rr;
                int col = n0 + wn*32 + tn*16 + lm;
                size_t o = (size_t)row*512 + col;
                float v = acc[tm][tn][rr];
                if (mode == 0) {
                    Pb[o] = (bf16)v;
                } else {
                    float nh = hf[o] + silu_f(v);
                    hf[o] = nh;
                    colsum[tn] += nh;
                    if (shp) shp[o] = (bf16)silu_f(nh);   // l==2: hb dead, sh needed
                    else     hb[o] = (bf16)nh;            // l<2: hb feeds next pgemm
                }
            }
        }
    }

    if (mode == 1 && shp) {           // l==2 fold: graph_repr + pred_noise + loss
        // graph_repr: column sums of final hf for this tile's 128 rows
        #pragma unroll
        for (int tn = 0; tn < 2; tn++) {
            float v = colsum[tn];
            v += __shfl_xor(v, 16, 64);
            v += __shfl_xor(v, 32, 64);
            if (q == 0) grbuf[w][tn*16 + lm] = v;
        }
        __syncthreads();
        if (((w & 1) == 0) && lane < 32) {
            float tot = grbuf[w][lane] + grbuf[w + 1][lane];
            int col = n0 + (w >> 1)*32 + lane;
            atomicAdd(&out_gr[(m0 >> 10)*512 + col], tot);
        }
        if (nt == 0) {
            // pred_noise + loss for units of rows m0..m0+127 (Zb final, written above)
            float per2 = 0.0f;
            #pragma unroll
            for (int j = 0; j < 2; j++) {
                int u = m0*4 + tid*2 + j;
                int b = u >> 2;
                #pragma unroll
                for (int d = 0; d < 3; d++) {
                    float dv = Zb[b*3 + d] - Zb0[b*3 + d];
                    out_pn[(size_t)u*3 + d] = dv;
                    float e = dv - noise[(size_t)u*3 + d];
                    per2 += e*e;
                }
            }
            #pragma unroll
            for (int off = 32; off >= 1; off >>= 1) per2 += __shfl_xor(per2, off, 64);
            if (lane == 0) lsh[w] = per2;
            __syncthreads();
            if (tid == 0)
                atomicAdd(out_loss, (lsh[0]+lsh[1]+lsh[2]+lsh[3]) * (1.0f/16.0f));
        }
    }
}

// distinct symbol per mode so rocprof shows each GEMM's true duration
template<int MODE>
__global__ __launch_bounds__(256) void gemm_mode_kernel(const bf16* __restrict__ A, const bf16* __restrict__ BT,
                                                        bf16* __restrict__ Pb, float* __restrict__ hf,
                                                        bf16* __restrict__ hb, bf16* __restrict__ shp,
                                                        const float* __restrict__ b1, const float* __restrict__ W2,
                                                        float* __restrict__ out_e,
                                                        float* __restrict__ Zb, const float* __restrict__ zacc,
                                                        const float* __restrict__ Zb0, const float* __restrict__ noise,
                                                        float* __restrict__ out_pn, float* __restrict__ out_loss,
                                                        float* __restrict__ out_gr) {
    gemm_body<1>(A, BT, Pb, hf, hb, shp, b1, W2, out_e, Zb, zacc,
                 Zb0, noise, out_pn, out_loss, out_gr, MODE, blockIdx.x);
}

// fused: [0,512) P-GEMM layer 0; [512,2560) KNN; [2560,4096) transposes l>0;
//        [4096,4108) ebias; [4108,4125) output zeroing
__global__ __launch_bounds__(256) void knn_pgemm0_kernel(const bf16* __restrict__ hb,
                                                         const bf16* __restrict__ WmT,
                                                         bf16* __restrict__ Pb,
                                                         const float* __restrict__ Zp,
                                                         const int* __restrict__ seg,
                                                         int* __restrict__ nbr,
                                                         const float* __restrict__ Wm,
                                                         const float* __restrict__ Wu,
                                                         const float* __restrict__ W1,
                                                         bf16* __restrict__ WmTw,
                                                         bf16* __restrict__ WuT,
                                                         bf16* __restrict__ W1T,
                                                         const float* __restrict__ edge_emb,
                                                         const float* __restrict__ We,
                                                         float* __restrict__ ebias,
                                                         float* __restrict__ out_gr,
                                                         float* __restrict__ out_e,
                                                         float* __restrict__ out_loss) {
    __shared__ float ttile[32][33];
    int bid = blockIdx.x, tid = threadIdx.x;
    if (bid < 512) {
        gemm_body<0>(hb, WmT, Pb, nullptr, nullptr, nullptr, nullptr, nullptr, nullptr,
                     nullptr, nullptr, nullptr, nullptr, nullptr, nullptr, nullptr, 0, bid);
        return;
    }
    if (bid < 2560) {
        knn_body(bid - 512, Zp, seg, nbr);
        return;
    }
    int tb = bid - 2560;
    if (tb < 1536) {   // 6 matrices (Wm l=1,2; Wu l=0..2; W1) x 256 tiles
        int z = 1 + (tb >> 8), rem = tb & 255;
        int bx = rem & 15, by = rem >> 4;
        int tx = tid & 31, ty = tid >> 5;     // 32 x 8
        const float* src; bf16* dst;
        if (z < 3)      { src = Wm + (size_t)z*262144;     dst = WmTw + (size_t)z*262144; }
        else if (z < 6) { src = Wu + (size_t)(z-3)*262144; dst = WuT + (size_t)(z-3)*262144; }
        else            { src = W1;                        dst = W1T; }
        #pragma unroll
        for (int i = 0; i < 32; i += 8)
            ttile[ty+i][tx] = src[(size_t)(by*32+ty+i)*512 + bx*32+tx];
        __syncthreads();
        #pragma unroll
        for (int i = 0; i < 32; i += 8)
            dst[(size_t)(bx*32+ty+i)*512 + by*32+tx] = (bf16)ttile[tx][ty+i];
        return;
    }
    tb -= 1536;
    if (tb < 12) {
        int gid = tb*256 + tid;
        int l = gid >> 10, t = (gid >> 9) & 1, c = gid & 511;
        float s = 0.0f;
        #pragma unroll 8
        for (int e = 0; e < 64; e++)
            s += edge_emb[t*64 + e] * We[(size_t)(l*64 + e)*512 + c];
        ebias[gid] = s;
        return;
    }
    tb -= 12;
    int k = tb*256 + tid;
    if (k < 4096) out_gr[k] = 0.0f;
    else if (k < 4104) out_e[k-4096] = 0.0f;
    else if (k == 4104) out_loss[0] = 0.0f;
}

// =================== edge aggregation: one WAVE per dst block, 8 ch/lane ===================
__global__ __launch_bounds__(256) void edge_kernel(const bf16* __restrict__ Pb, const float* __restrict__ ebias,
                                                   const float* __restrict__ wz, const float* __restrict__ Zb,
                                                   const int* __restrict__ nbr, bf16* __restrict__ msum,
                                                   float* __restrict__ zacc) {
    int bid = blockIdx.x, tid = threadIdx.x;
    int lane = tid & 63, wid = tid >> 6;
    int b = ((bid & 7) << 10) | ((bid >> 3) << 2) | wid;   // XCD-local graph, 4 dst blocks/block
    __shared__ int srcs[4][18];
    if (tid < 72) {
        int w2 = tid / 18, e2 = tid - w2*18;
        int bb = ((bid & 7) << 10) | ((bid >> 3) << 2) | w2;
        srcs[w2][e2] = nbr[bb*18 + e2];
    }
    __syncthreads();
    int c0 = lane << 3;     // 8 channels per lane
    float pd[8], eb0[8], eb1[8], wv[8];
    unpack8(Pb + (size_t)b*512 + c0, pd);
    *(float4*)(eb0)   = *(const float4*)(ebias + c0);
    *(float4*)(eb0+4) = *(const float4*)(ebias + c0 + 4);
    *(float4*)(eb1)   = *(const float4*)(ebias + 512 + c0);
    *(float4*)(eb1+4) = *(const float4*)(ebias + 512 + c0 + 4);
    *(float4*)(wv)    = *(const float4*)(wz + c0);
    *(float4*)(wv+4)  = *(const float4*)(wz + c0 + 4);
    float ms[8];
    #pragma unroll
    for (int j = 0; j < 8; j++) ms[j] = 0.0f;
    float pdot[18];
    #pragma unroll
    for (int e = 0; e < 18; e++) {
        int s = srcs[wid][e];
        float pv[8];
        unpack8(Pb + (size_t)s*512 + c0, pv);
        float dot = 0.0f;
        #pragma unroll
        for (int j = 0; j < 8; j++) {
            float base = (e < 9) ? eb0[j] : eb1[j];     // e compile-time after unroll
            float m = silu_f(pv[j] + pd[j] + base);
            ms[j] += m;
            dot += m * wv[j];
        }
        pdot[e] = dot;
    }
    bf16x8 mp;
    #pragma unroll
    for (int j = 0; j < 8; j++) mp[j] = (bf16)ms[j];
    *(bf16x8*)(msum + (size_t)b*512 + c0) = mp;
    // wave-reduce each pdot[e] (butterfly -> every lane has full sum)
    #pragma unroll
    for (int e = 0; e < 18; e++) {
        float v = pdot[e];
        #pragma unroll
        for (int off = 32; off >= 1; off >>= 1) v += __shfl_xor(v, off, 64);
        pdot[e] = v;
    }
    // lane e takes edge e: select own dot, tanh, z-term; reduce 3 comps over lanes
    float dotv = 0.0f;
    #pragma unroll
    for (int e = 0; e < 18; e++) dotv = (lane == e) ? pdot[e] : dotv;
    float coef = tanhf(dotv);
    float t3[3] = {0.0f, 0.0f, 0.0f};
    if (lane < 18) {
        int se = srcs[wid][lane];
        #pragma unroll
        for (int d = 0; d < 3; d++)
            t3[d] = (Zb[se*3 + d] - Zb[b*3 + d]) * coef;
    }
    #pragma unroll
    for (int off = 16; off >= 1; off >>= 1) {
        t3[0] += __shfl_xor(t3[0], off, 64);
        t3[1] += __shfl_xor(t3[1], off, 64);
        t3[2] += __shfl_xor(t3[2], off, 64);
    }
    if (lane == 0) {
        zacc[b*3 + 0] = t3[0];
        zacc[b*3 + 1] = t3[1];
        zacc[b*3 + 2] = t3[2];
    }
}

// =================== unit_repr (float4) ===================
__global__ __launch_bounds__(256) void unitrepr_kernel(const int* __restrict__ Aarr, const int* __restrict__ posa,
                                                       const int* __restrict__ Barr,
                                                       const float* __restrict__ atom_emb, const float* __restrict__ pos_emb,
                                                       const float* __restrict__ block_emb,
                                                       const float* __restrict__ hf, float* __restrict__ out_ur) {
    int gid = blockIdx.x*256 + threadIdx.x;      // 32768 units x 128 threads
    int u = gid >> 7, c = (gid & 127) << 2, b = u >> 2;
    float4 va = *(const float4*)(atom_emb + (size_t)Aarr[u]*512 + c);
    float4 vp = *(const float4*)(pos_emb + (size_t)posa[u]*512 + c);
    float4 vb = *(const float4*)(block_emb + (size_t)Barr[b]*512 + c);
    float4 vh = *(const float4*)(hf + (size_t)b*512 + c);
    float4 o;
    o.x = va.x + vp.x + vb.x + vh.x;
    o.y = va.y + vp.y + vb.y + vh.y;
    o.z = va.z + vp.z + vb.z + vh.z;
    o.w = va.w + vp.w + vb.w + vh.w;
    *(float4*)(out_ur + (size_t)u*512 + c) = o;
}

extern "C" void kernel_launch(void* const* d_in, const int* in_sizes, int n_in,
                              void* d_out, int out_size, void* d_ws, size_t ws_size,
                              hipStream_t stream) {
    const float* Z         = (const float*)d_in[0];
    const int*   B         = (const int*)d_in[1];
    const int*   A         = (const int*)d_in[2];
    const int*   ap        = (const int*)d_in[3];
    const int*   seg       = (const int*)d_in[6];
    const float* noise     = (const float*)d_in[7];
    const int*   nl        = (const int*)d_in[8];
    const float* sig       = (const float*)d_in[9];
    const float* atom_emb  = (const float*)d_in[10];
    const float* pos_emb   = (const float*)d_in[11];
    const float* block_emb = (const float*)d_in[12];
    const float* edge_emb  = (const float*)d_in[13];
    const float* Wm        = (const float*)d_in[14];
    const float* We        = (const float*)d_in[15];
    const float* Wu        = (const float*)d_in[16];
    const float* wz        = (const float*)d_in[17];
    const float* W1        = (const float*)d_in[18];
    const float* b1        = (const float*)d_in[19];
    const float* W2        = (const float*)d_in[20];
    (void)in_sizes; (void)n_in; (void)d_ws; (void)ws_size; (void)out_size;

    float* out = (float*)d_out;
    const size_t o1 = 8, o2 = 98312, o3 = 16875528, o4 = 21069832, o5 = 21073928;
    float* out_e    = out;
    float* out_pn   = out + o1;
    float* out_ur   = out + o2;
    float* hf       = out + o3;   // block_repr == final h (fp32), updated in place
    float* out_gr   = out + o4;
    float* out_loss = out + o5;

    // scratch arena inside the unit_repr output region (67 MB); unit_repr written last
    char* arena = (char*)(out + o2);
    bf16*  Pb   = (bf16*)(arena);                  // 8 MB
    bf16*  msum = (bf16*)(arena + 16777216);       // 8 MB
    bf16*  sh   = (bf16*)(arena + 25165824);       // 8 MB
    bf16*  hb   = (bf16*)(arena + 33554432);       // 8 MB
    float* Zp   = (float*)(arena + 41943040);
    float* Zb0  = (float*)(arena + 42336256);
    float* Zb   = (float*)(arena + 42434560);
    float* zacc = (float*)(arena + 42532864);
    int*   nbr  = (int*)  (arena + 42631168);
    bf16*  WmT  = (bf16*) (arena + 43220992);
    bf16*  WuT  = (bf16*) (arena + 44793856);
    bf16*  W1T  = (bf16*) (arena + 46366720);
    float* ebias= (float*)(arena + 46891008);

    init_kernel<<<8192 + 256, 256, 0, stream>>>(
        Z, noise, nl, sig, A, ap, B, atom_emb, pos_emb, block_emb,
        Wm, Zp, Zb0, Zb, hf, hb, WmT);

    knn_pgemm0_kernel<<<512 + 2048 + 1536 + 12 + 17, 256, 0, stream>>>(
        hb, WmT, Pb, Zp, seg, nbr,
        Wm, Wu, W1, WmT, WuT, W1T,
        edge_emb, We, ebias, out_gr, out_e, out_loss);

    for (int l = 0; l < 3; l++) {
        if (l > 0)
            gemm_mode_kernel<0><<<512, 256, 0, stream>>>(hb, WmT + (size_t)l*262144, Pb,
                                                 nullptr, nullptr, nullptr, nullptr, nullptr, nullptr,
                                                 nullptr, nullptr, nullptr, nullptr, nullptr, nullptr, nullptr);
        edge_kernel<<<2048, 256, 0, stream>>>(Pb, ebias + l*1024, wz + l*512, Zb, nbr, msum, zacc);
        gemm_mode_kernel<1><<<512, 256, 0, stream>>>(msum, WuT + (size_t)l*262144, nullptr,
                                             hf, hb, (l == 2) ? sh : nullptr, nullptr, nullptr, nullptr,
                                             Zb, zacc, Zb0, noise, out_pn, out_loss, out_gr);
    }
    gemm_mode_kernel<2><<<512, 256, 0, stream>>>(sh, W1T, nullptr, nullptr, nullptr, nullptr,
                                         b1, W2, out_e, nullptr, nullptr,
                                         nullptr, nullptr, nullptr, nullptr, nullptr);
    // unit_repr last: overwrites the scratch arena
    unitrepr_kernel<<<16384, 256, 0, stream>>>(A, ap, B, atom_emb, pos_emb, block_emb, hf, out_ur);
}